// Round 15
// baseline (46.572 us; speedup 1.0000x reference)
//
#include <hip/hip_runtime.h>
#include <math.h>

#define BB 4
#define C 64
#define H 128
#define W 128
#define HW (H*W)
#define KC 576            // GEMM K dim: col = k*64 + c
#define XR 6              // x-window rows
#define XC 38             // x-window cols
#define CR 4              // c-window rows
#define CCW 34            // c-window cols
#define OFFS 28           // offT per-pixel stride (f16)

typedef __attribute__((ext_vector_type(4))) float f32x4;
typedef __attribute__((ext_vector_type(4))) _Float16 f16x4;
typedef __attribute__((ext_vector_type(8))) _Float16 f16x8;

static __device__ __forceinline__ f16x8 splat8(float f) {
  _Float16 h = (_Float16)f;
  f16x8 v = {h, h, h, h, h, h, h, h};
  return v;
}

// ---------------- kernel 1: transpose x,c to NHWC f16 + frag-major weight prep
__global__ __launch_bounds__(256) void xpose_prep_kernel(
    const float* __restrict__ x, const float* __restrict__ cin,
    const float* __restrict__ wd, const float* __restrict__ woff,
    _Float16* __restrict__ xt, _Float16* __restrict__ ct,
    _Float16* __restrict__ wtbf, _Float16* __restrict__ wotf) {
  __shared__ _Float16 lds16[32 * 72];
  int t = threadIdx.x;

  if (blockIdx.y == 1 && blockIdx.x < 144) {
    int i = blockIdx.x * 256 + t;          // 0..36863
    {  // wtbf: [kb*4+ot][lane][8] <- w_dcn  (A-frag-major, coalesced loads)
      int j = i & 7, ln = (i >> 3) & 63, fi = i >> 9;   // fi 0..71
      int ot = fi & 3, kb = fi >> 2;
      int o = ot * 16 + (ln & 15);
      int kcol = kb * 32 + (ln >> 4) * 8 + j;
      int k = kcol >> 6, cc = kcol & 63;
      wtbf[i] = (_Float16)wd[(o * C + cc) * 9 + k];
    }
    if (i < 32 * KC) {  // wotf: [kb*2+ot2][lane][8] <- w_off (rows>=27 -> 0)
      int j = i & 7, ln = (i >> 3) & 63, fi = i >> 9;   // fi 0..35
      int ot2 = fi & 1, kb = fi >> 1;
      int o = ot2 * 16 + (ln & 15);
      int kcol = kb * 32 + (ln >> 4) * 8 + j;
      int k = kcol >> 6, cc = kcol & 63;
      wotf[i] = (o < 27) ? (_Float16)woff[(o * C + cc) * 9 + k] : (_Float16)0.f;
    }
  }

  const float* src = blockIdx.y ? cin : x;
  _Float16* dst = blockIdx.y ? ct : xt;

  int P0 = blockIdx.x * 32;
  int b = P0 >> 14;
  int pp0 = P0 & (HW - 1);

  int p = t & 31;
  int cg = t >> 5;
  const float* xb = src + (size_t)b * C * HW + pp0 + p;
  f16x8 u;
#pragma unroll
  for (int j = 0; j < 8; ++j)
    u[j] = (_Float16)xb[(cg * 8 + j) * HW];
  *(f16x8*)(lds16 + p * 72 + ((cg ^ (p & 7)) << 3)) = u;

  __syncthreads();

  int q = t >> 3;
  int s = t & 7;
  f16x8 v = *(const f16x8*)(lds16 + q * 72 + ((s ^ (q & 7)) << 3));
  *(f16x8*)(dst + (size_t)(P0 + q) * 64 + s * 8) = v;
}

// ---------------- kernel 2: fused DCN, pixel-paired MFMA (A-frag reuse x2)
// 128 thr = 2 waves; wave owns one row's 32 px. LDS = 32768 B (5 blk/CU cap).
__global__ __launch_bounds__(128, 2) void dcn_fused_kernel(
    const _Float16* __restrict__ xt, const _Float16* __restrict__ ct,
    const _Float16* __restrict__ wtbf, const _Float16* __restrict__ wotf,
    const float* __restrict__ boff, const float* __restrict__ bd,
    float* __restrict__ out) {
  __shared__ __align__(16) unsigned char smem[32768];
  _Float16* win  = (_Float16*)smem;                 // windows (overlaid)
  _Float16* offT = (_Float16*)(smem + 29184);       // [2][32][28] f16

  int tid = threadIdx.x;
  int bid = blockIdx.x;
  int w0 = (bid & 3) * 32;
  int h0 = ((bid >> 2) & 63) * 2;
  int b  = bid >> 8;

  int lane = tid & 63;
  int wv = tid >> 6;            // wave = row
  int lr = lane & 15, lh = lane >> 4;
  int h = h0 + wv;              // wave-uniform row

  const _Float16* xtb = xt + (size_t)b * HW * 64;
  const _Float16* ctb = ct + (size_t)b * HW * 64;

  int crlo = min(max(h0 - 1, 0), H - CR);
  int cclo = min(max(w0 - 1, 0), W - CCW);
  int rlo  = min(max(h0 - 2, 0), H - XR);
  int clo  = min(max(w0 - 3, 0), W - XC);

  // ---- stage c-window (4 x 34), coalesced full lines ----
#pragma unroll
  for (int g = 0; g < 9; ++g) {
    int cch = g * 128 + tid;                 // 16-B chunks, 1088 total
    if (cch < CR * CCW * 8) {
      int pixw = cch >> 3, part = cch & 7;
      int row = pixw / CCW, col = pixw - row * CCW;
      *(f16x8*)(win + (size_t)pixw * 64 + ((part ^ (pixw & 7)) << 3)) =
        *(const f16x8*)(ctb + ((size_t)(crlo + row) * W + cclo + col) * 64 + part * 8);
    }
  }
  __syncthreads();

  // ---- GEMM1: off[32o][32px]; one A-load feeds both pixel-halves ----
  f32x4 acc00 = {0.f,0.f,0.f,0.f};   // o 0-15  x px 0-15
  f32x4 acc01 = {0.f,0.f,0.f,0.f};   // o 0-15  x px 16-31
  f32x4 acc10 = {0.f,0.f,0.f,0.f};   // o 16-31 x px 0-15
  f32x4 acc11 = {0.f,0.f,0.f,0.f};   // o 16-31 x px 16-31
#pragma unroll 2
  for (int kb = 0; kb < 18; ++kb) {
    int t9 = kb >> 1;
    int cg = (kb & 1) * 4 + lh;
    int ty = h + t9 / 3 - 1;
    int txA = w0 + lr + t9 % 3 - 1;
    int txB = txA + 16;
    bool okA = (ty >= 0) && (ty < H) && (txA >= 0) && (txA < W);
    bool okB = (ty >= 0) && (ty < H) && (txB >= 0) && (txB < W);
    int tyc = min(max(ty, 0), H - 1) - crlo;
    int pwA = tyc * CCW + (min(max(txA, 0), W - 1) - cclo);
    int pwB = tyc * CCW + (min(max(txB, 0), W - 1) - cclo);
    f16x8 b0 = *(const f16x8*)(win + (size_t)pwA * 64 + ((cg ^ (pwA & 7)) << 3));
    f16x8 b1 = *(const f16x8*)(win + (size_t)pwB * 64 + ((cg ^ (pwB & 7)) << 3));
    if (!okA) b0 = splat8(0.f);
    if (!okB) b1 = splat8(0.f);
    f16x8 a0 = *(const f16x8*)(wotf + ((size_t)(kb * 2 + 0) * 64 + lane) * 8);
    f16x8 a1 = *(const f16x8*)(wotf + ((size_t)(kb * 2 + 1) * 64 + lane) * 8);
    acc00 = __builtin_amdgcn_mfma_f32_16x16x32_f16(a0, b0, acc00, 0, 0, 0);
    acc01 = __builtin_amdgcn_mfma_f32_16x16x32_f16(a0, b1, acc01, 0, 0, 0);
    acc10 = __builtin_amdgcn_mfma_f32_16x16x32_f16(a1, b0, acc10, 0, 0, 0);
    acc11 = __builtin_amdgcn_mfma_f32_16x16x32_f16(a1, b1, acc11, 0, 0, 0);
  }

  // offT[wv][px][o] = f16(acc + bias)   (C/D: col=lr -> px, row=lh*4+r -> o)
  {
    f16x4 v00, v01, v10, v11;
#pragma unroll
    for (int r = 0; r < 4; ++r) {
      int o0 = lh * 4 + r;
      int o1 = 16 + lh * 4 + r;
      float b0v = boff[o0];
      float b1v = (o1 < 27) ? boff[o1] : 0.f;
      v00[r] = (_Float16)(acc00[r] + b0v);
      v01[r] = (_Float16)(acc01[r] + b0v);
      v10[r] = (_Float16)(acc10[r] + b1v);
      v11[r] = (_Float16)(acc11[r] + b1v);
    }
    _Float16* baseA = offT + ((size_t)wv * 32 + lr) * OFFS;
    _Float16* baseB = offT + ((size_t)wv * 32 + 16 + lr) * OFFS;
    *(f16x4*)(baseA + lh * 4) = v00;
    *(f16x4*)(baseB + lh * 4) = v01;
    if (lh < 3) { *(f16x4*)(baseA + 16 + lh * 4) = v10;
                  *(f16x4*)(baseB + 16 + lh * 4) = v11; }
  }
  __syncthreads();   // c-window reads done -> x-stage may overwrite win

  // ---- stage x-window (6 x 38) + pull both pixels' offsets (disjoint LDS) --
#pragma unroll
  for (int g = 0; g < 15; ++g) {
    int cch = g * 128 + tid;                 // 1824 chunks
    if (cch < XR * XC * 8) {
      int pixw = cch >> 3, part = cch & 7;
      int row = pixw / XC, col = pixw - row * XC;
      *(f16x8*)(win + (size_t)pixw * 64 + ((part ^ (pixw & 7)) << 3)) =
        *(const f16x8*)(xtb + ((size_t)(rlo + row) * W + clo + col) * 64 + part * 8);
    }
  }
  f16x4 rv0[7], rv1[7];
#pragma unroll
  for (int j = 0; j < 7; ++j) {
    rv0[j] = *(const f16x4*)(offT + ((size_t)wv * 32 + lr) * OFFS + 4 * j);
    rv1[j] = *(const f16x4*)(offT + ((size_t)wv * 32 + 16 + lr) * OFFS + 4 * j);
  }
  __syncthreads();

#define OFFV0(i) ((float)rv0[(i) >> 2][(i) & 3])
#define OFFV1(i) ((float)rv1[(i) >> 2][(i) & 3])

  // ---- sample + GEMM2: per kb one A-load, two B (px-pairs) ----
  f32x4 acc[4][2];
#pragma unroll
  for (int i = 0; i < 4; ++i) { acc[i][0] = (f32x4){0.f,0.f,0.f,0.f};
                                acc[i][1] = (f32x4){0.f,0.f,0.f,0.f}; }

#pragma unroll
  for (int k = 0; k < 9; ++k) {
    // per-pixel-pair sampling state
    float w00[2], w01[2], w10[2], w11[2];
    int p00[2], p01[2], p10[2], p11[2];
    bool in00[2], in01[2], in10[2], in11[2];
    int yc0[2], yc1[2], xc0[2], xc1[2];
#pragma unroll
    for (int P = 0; P < 2; ++P) {
      float dy = P ? OFFV1(2 * k)     : OFFV0(2 * k);
      float dx = P ? OFFV1(2 * k + 1) : OFFV0(2 * k + 1);
      float mv = P ? OFFV1(18 + k)    : OFFV0(18 + k);
      float m = 1.0f / (1.0f + __expf(-mv));
      int wpx = w0 + P * 16 + lr;

      float py = (float)(h + k / 3 - 1) + dy;
      float px = (float)(wpx + k % 3 - 1) + dx;
      float y0f = floorf(py), x0f = floorf(px);
      int y0 = (int)y0f, x0 = (int)x0f;
      float wy1 = py - y0f, wx1 = px - x0f;
      float wy0 = 1.0f - wy1, wx0 = 1.0f - wx1;

      bool y0v = (y0 >= 0) && (y0 < H);
      bool y1v = (y0 + 1 >= 0) && (y0 + 1 < H);
      bool x0v = (x0 >= 0) && (x0 < W);
      bool x1v = (x0 + 1 >= 0) && (x0 + 1 < W);
      int y0c = min(max(y0, 0), H - 1), y1c = min(max(y0 + 1, 0), H - 1);
      int x0c = min(max(x0, 0), W - 1), x1c = min(max(x0 + 1, 0), W - 1);
      yc0[P] = y0c; yc1[P] = y1c; xc0[P] = x0c; xc1[P] = x1c;

      w00[P] = wy0 * wx0 * (float)(y0v && x0v) * m;
      w01[P] = wy0 * wx1 * (float)(y0v && x1v) * m;
      w10[P] = wy1 * wx0 * (float)(y1v && x0v) * m;
      w11[P] = wy1 * wx1 * (float)(y1v && x1v) * m;

      int iy0 = y0c - rlo, iy1 = y1c - rlo;
      int ix0 = x0c - clo, ix1 = x1c - clo;
      bool inY0 = (unsigned)iy0 < XR, inY1 = (unsigned)iy1 < XR;
      bool inX0 = (unsigned)ix0 < XC, inX1 = (unsigned)ix1 < XC;
      in00[P] = inY0 && inX0; in01[P] = inY0 && inX1;
      in10[P] = inY1 && inX0; in11[P] = inY1 && inX1;
      int jy0 = min(max(iy0, 0), XR - 1), jy1 = min(max(iy1, 0), XR - 1);
      int jx0 = min(max(ix0, 0), XC - 1), jx1 = min(max(ix1, 0), XC - 1);
      p00[P] = jy0 * XC + jx0; p01[P] = jy0 * XC + jx1;
      p10[P] = jy1 * XC + jx0; p11[P] = jy1 * XC + jx1;
    }

#pragma unroll
    for (int half = 0; half < 2; ++half) {
      int cg = half * 4 + lh;
      f16x8 s[2];
#pragma unroll
      for (int P = 0; P < 2; ++P) {
        f16x8 c00 = *(const f16x8*)(win + (size_t)p00[P] * 64 + ((cg ^ (p00[P] & 7)) << 3));
        f16x8 c01 = *(const f16x8*)(win + (size_t)p01[P] * 64 + ((cg ^ (p01[P] & 7)) << 3));
        f16x8 c10 = *(const f16x8*)(win + (size_t)p10[P] * 64 + ((cg ^ (p10[P] & 7)) << 3));
        f16x8 c11 = *(const f16x8*)(win + (size_t)p11[P] * 64 + ((cg ^ (p11[P] & 7)) << 3));
        // rare fallback: sample outside staged window (exec-masked)
        if (!in00[P]) c00 = *(const f16x8*)(xtb + ((size_t)yc0[P] * W + xc0[P]) * 64 + cg * 8);
        if (!in01[P]) c01 = *(const f16x8*)(xtb + ((size_t)yc0[P] * W + xc1[P]) * 64 + cg * 8);
        if (!in10[P]) c10 = *(const f16x8*)(xtb + ((size_t)yc1[P] * W + xc0[P]) * 64 + cg * 8);
        if (!in11[P]) c11 = *(const f16x8*)(xtb + ((size_t)yc1[P] * W + xc1[P]) * 64 + cg * 8);

        f16x8 sv = c00 * splat8(w00[P]);
        sv += c01 * splat8(w01[P]);
        sv += c10 * splat8(w10[P]);
        sv += c11 * splat8(w11[P]);
        s[P] = sv;                      // B-fragment for kb, pixel-pair P
      }

      int kb = 2 * k + half;
#pragma unroll
      for (int ot = 0; ot < 4; ++ot) {
        f16x8 a = *(const f16x8*)(wtbf + ((size_t)(kb * 4 + ot) * 64 + lane) * 8);
        acc[ot][0] = __builtin_amdgcn_mfma_f32_16x16x32_f16(a, s[0], acc[ot][0], 0, 0, 0);
        acc[ot][1] = __builtin_amdgcn_mfma_f32_16x16x32_f16(a, s[1], acc[ot][1], 0, 0, 0);
      }
    }
  }

  // ---- epilogue ----
#pragma unroll
  for (int ot = 0; ot < 4; ++ot) {
#pragma unroll
    for (int r = 0; r < 4; ++r) {
      int o = ot * 16 + lh * 4 + r;
      float bias = bd[o];
      size_t base = ((size_t)(b * C + o)) * HW + (size_t)h * W + w0 + lr;
      out[base]      = acc[ot][0][r] + bias;
      out[base + 16] = acc[ot][1][r] + bias;
    }
  }
}

extern "C" void kernel_launch(void* const* d_in, const int* in_sizes, int n_in,
                              void* d_out, int out_size, void* d_ws, size_t ws_size,
                              hipStream_t stream) {
  const float* x    = (const float*)d_in[0];
  const float* c    = (const float*)d_in[1];
  const float* woff = (const float*)d_in[2];
  const float* boff = (const float*)d_in[3];
  const float* wdcn = (const float*)d_in[4];
  const float* bdcn = (const float*)d_in[5];
  float* out = (float*)d_out;

  _Float16* xt   = (_Float16*)d_ws;                   // 4,194,304 f16
  _Float16* ct   = xt + 4194304;                      // 4,194,304 f16
  _Float16* wtbf = ct + 4194304;                      // 36,864 f16
  _Float16* wotf = wtbf + 36864;                      // 18,432 f16

  int npix = BB * H * W;                              // 65536
  dim3 gx(npix / 32, 2);
  xpose_prep_kernel<<<gx, 256, 0, stream>>>(x, c, wdcn, woff, xt, ct, wtbf, wotf);
  dcn_fused_kernel<<<npix / 64, 128, 0, stream>>>(xt, ct, wtbf, wotf, boff, bdcn, out);
}